// Round 7
// baseline (232.631 us; speedup 1.0000x reference)
//
#include <hip/hip_runtime.h>
#include <hip/hip_bf16.h>

#define N_NODES 50000
#define HD 128
#define NTILES (N_NODES / 16)   // 3125, exact
#define GRID 256                // one block per CU; residency-guaranteed
#define BLK 512                 // 8 waves/block
#define WPB 8
#define NG 32                   // vaccp shards: 8-deep atomic chains
#define NCELL 32                // barrier counter shards: 8-deep arrive chains

using short8  = __attribute__((ext_vector_type(8))) short;   // 8 x bf16 bits
using floatx4 = __attribute__((ext_vector_type(4))) float;

__device__ __forceinline__ short f2bf(float f) {
  union { float fp; unsigned u; } un; un.fp = f;
  unsigned u = un.u + 0x7fffu + ((un.u >> 16) & 1u);   // RNE
  return (short)(u >> 16);
}

// Sharded grid barrier. R1/R2 lesson: a SINGLE arrive counter serializes 256
// clustered release-RMWs at ~125ns each (~33us/barrier, matching both mega
// runs). 32 cells (128B apart) cut the chain to 8-deep (~1us). Poll: lanes
// 0..31 LOAD the cells (no ownership traffic), wave-reduce, compare.
// __syncthreads first => all of this block's atomics are vmcnt-drained and
// thus visible at the coherence point before we arrive. Deadlock-free: 256
// blocks always co-resident (<= 1:1 with CUs even under worst packing).
__device__ __forceinline__ void gridbar(unsigned* cells, unsigned target) {
  __syncthreads();
  if (threadIdx.x == 0)
    __hip_atomic_fetch_add(&cells[(blockIdx.x & (NCELL - 1)) * 32], 1u,
                           __ATOMIC_RELEASE, __HIP_MEMORY_SCOPE_AGENT);
  if (threadIdx.x < 64) {
    unsigned sum;
    do {
      unsigned v = (threadIdx.x < NCELL)
          ? __hip_atomic_load(&cells[threadIdx.x * 32], __ATOMIC_RELAXED,
                              __HIP_MEMORY_SCOPE_AGENT)
          : 0u;
#pragma unroll
      for (int off = 32; off > 0; off >>= 1) v += __shfl_xor(v, off, 64);
      sum = v;
      if (sum < target) __builtin_amdgcn_s_sleep(8);
    } while (sum < target);
    __builtin_amdgcn_fence(__ATOMIC_ACQUIRE, "agent");
  }
  __syncthreads();
}

// ================== single persistent kernel, v2 ==================
// Phase A: deg[dst] += 1 (f32 atomics, 50k addresses, ~16-deep avg)
// barrier | Phase C: s[src] += rsqrt(1+deg[dst]) | barrier
// Phase E: MFMA weighted sum, w computed inline from deg/s
// Phase F: head, by last-arriver election (sharded cells, benign dup).
// No partial[64][50000] intermediate (-50MB traffic, -2 phases).
#define LOADT(p, t) do {                                                  \
    const float* xr_ = xbase + (size_t)((t) * 16 + col) * HD + quad * 8;  \
    _Pragma("unroll") for (int kk = 0; kk < 4; ++kk) {                    \
      p##0[kk] = *(const floatx4*)(xr_ + kk * 32);                        \
      p##1[kk] = *(const floatx4*)(xr_ + kk * 32 + 4);                    \
    }                                                                     \
    p##d = *(const floatx4*)&degf[(t) * 16 + quad * 4];                   \
    p##s = *(const floatx4*)&sarr[(t) * 16 + quad * 4];                   \
  } while (0)

#define COMPUTE(p) do {                                                   \
    floatx4 acc[8] = {};                                                  \
    _Pragma("unroll") for (int kt = 0; kt < 4; ++kt) {                    \
      short8 a;                                                           \
      _Pragma("unroll") for (int j = 0; j < 4; ++j) {                     \
        a[j] = f2bf(p##0[kt][j]); a[j + 4] = f2bf(p##1[kt][j]); }         \
      _Pragma("unroll") for (int t = 0; t < 8; ++t) {                     \
        short8 bfr = *(const short8*)&lW[((kt * 8 + t) * 64 + lane) * 8]; \
        acc[t] = __builtin_amdgcn_mfma_f32_16x16x32_bf16(a, bfr, acc[t], 0, 0, 0); } } \
    floatx4 w4_;                                                          \
    _Pragma("unroll") for (int r = 0; r < 4; ++r) {                       \
      float dv_ = rsqrtf(1.0f + p##d[r]);                                 \
      w4_[r] = dv_ * (p##s[r] + dv_); }                                   \
    _Pragma("unroll") for (int t = 0; t < 8; ++t)                         \
      _Pragma("unroll") for (int r = 0; r < 4; ++r) {                     \
        float y = acc[t][r] + bias[t];                                    \
        pv[t] += fmaxf(y, 0.f) * w4_[r]; }                                \
  } while (0)

__global__ __launch_bounds__(BLK, 2) void k_mega2(
    const float* __restrict__ x, const int* __restrict__ src,
    const int* __restrict__ dst, const float* __restrict__ Wf,
    const float* __restrict__ bfeat,
    const float* __restrict__ Wg, const float* __restrict__ bg,
    const float* __restrict__ W1, const float* __restrict__ b1,
    const float* __restrict__ W2, const float* __restrict__ b2,
    float* __restrict__ degf, float* __restrict__ sarr,
    float* __restrict__ vaccp, unsigned* __restrict__ cells,
    float* __restrict__ out, int E) {
  __shared__ __align__(16) short lW[32 * 64 * 8];   // 32 KB W-fragments
  __shared__ float red[WPB * HD];                   // 4 KB reduce scratch
  __shared__ int lastf;
  const int tid = threadIdx.x;
  const int bx  = blockIdx.x;

  // ---- stage Wf B-fragments (independent of edge phases; overlaps A) ----
  for (int c = tid; c < 2048; c += BLK) {           // c = (kt*8+t)*64 + lane
    int lane = c & 63, t = (c >> 6) & 7, kt = c >> 9;
    int h = t * 16 + (lane & 15);
    int dbase = kt * 32 + (lane >> 4) * 8;
    short8 v;
#pragma unroll
    for (int j = 0; j < 8; ++j) v[j] = f2bf(Wf[(dbase + j) * HD + h]);
    *(short8*)&lW[c * 8] = v;
  }

  // ---- phase A: degree (f32 atomics; degf pre-zeroed by host memset) ----
  const int perBlk = (E + GRID - 1) / GRID;
  const int e0 = bx * perBlk;
  const int e1 = min(e0 + perBlk, E);
  for (int e = e0 + tid; e < e1; e += BLK)
    atomicAdd(&degf[dst[e]], 1.0f);

  gridbar(cells, GRID);

  // ---- phase C: s[src] += dinv[dst], dinv recomputed on the fly ----
  for (int e = e0 + tid; e < e1; e += BLK) {
    float dv = rsqrtf(1.0f + degf[dst[e]]);
    atomicAdd(&sarr[src[e]], dv);
  }

  gridbar(cells, 2u * GRID);

  // ---- phase E: vaccp[g,b,h] += sum_n w[n]*relu(x[b,n,:]@Wf + bf)[h] ----
  const int lane = tid & 63;
  const int wave = tid >> 6;
  const int col  = lane & 15;
  const int quad = lane >> 4;
  const int gw   = bx * WPB + wave;    // 0..2047
  const int b    = gw & 1;

  float bias[8];
#pragma unroll
  for (int t = 0; t < 8; ++t) bias[t] = bfeat[t * 16 + col];
  float pv[8];
#pragma unroll
  for (int t = 0; t < 8; ++t) pv[t] = 0.f;

  const float* xbase = x + (size_t)b * N_NODES * HD;
  const int t0 = gw >> 1;              // 0..1023
  const int stride = 1024;

  floatx4 xA0[4], xA1[4], xB0[4], xB1[4];
  floatx4 xAd = {}, xAs = {}, xBd = {}, xBs = {};
  LOADT(xA, t0);
  for (int tile = t0; tile < NTILES; tile += 2 * stride) {
    const int t1 = tile + stride, t2 = tile + 2 * stride;
    if (t1 < NTILES) LOADT(xB, t1);    // wave-uniform branch
    COMPUTE(xA);
    if (t2 < NTILES) LOADT(xA, t2);
    if (t1 < NTILES) COMPUTE(xB);
  }

  // cross-wave LDS reduce, then ONE atomic per (g,b,h) per block (8-deep)
  __syncthreads();
#pragma unroll
  for (int t = 0; t < 8; ++t) {
    float v = pv[t];
    v += __shfl_xor(v, 32, 64);
    v += __shfl_xor(v, 16, 64);
    if (quad == 0) red[wave * 128 + t * 16 + col] = v;
  }
  __syncthreads();
  if (tid < 256) {
    int hb = tid >> 7, h = tid & 127;
    float v = red[hb * 128 + h] + red[(hb + 2) * 128 + h] +
              red[(hb + 4) * 128 + h] + red[(hb + 6) * 128 + h];
    atomicAdd(&vaccp[((bx & (NG - 1)) * 2 + hb) * HD + h], v);
  }

  // ---- phase F election: sharded cells; duplicates are benign ----
  __syncthreads();                     // vaccp atomics drained (vmcnt)
  if (tid == 0)
    __hip_atomic_fetch_add(&cells[(bx & (NCELL - 1)) * 32], 1u,
                           __ATOMIC_RELEASE, __HIP_MEMORY_SCOPE_AGENT);
  if (tid < 64) {
    unsigned v = (tid < NCELL)
        ? __hip_atomic_load(&cells[tid * 32], __ATOMIC_RELAXED,
                            __HIP_MEMORY_SCOPE_AGENT)
        : 0u;
#pragma unroll
    for (int off = 32; off > 0; off >>= 1) v += __shfl_xor(v, off, 64);
    if (tid == 0) lastf = (v >= 3u * GRID) ? 1 : 0;
  }
  __syncthreads();
  if (!lastf) return;
  __builtin_amdgcn_fence(__ATOMIC_ACQUIRE, "agent");

  // ---- phase F: tiny head (last block only; 512 threads, 2-way k-split) --
  {
    float* vsum   = (float*)lW;            // 256 floats
    float* pooled = vsum + 256;            // 256
    float* zz     = pooled + 256;          // 256
    float* part   = zz + 256;              // 2*256
    float* rf     = part + 512;            // 256
    const int kq = tid >> 8;               // 0/1
    const int pr = tid & 255;
    const int hb = pr >> 7, h = pr & 127;
    if (tid < 256) {
      float a = 0.f;
#pragma unroll
      for (int g = 0; g < NG; ++g) a += vaccp[g * 256 + tid];
      vsum[tid] = a;
    }
    __syncthreads();
    {
      const int k0 = kq * 64;
      float acc = 0.f;
#pragma unroll
      for (int k = 0; k < 64; ++k)
        acc += vsum[hb * HD + k0 + k] * Wg[(k0 + k) * HD + h];
      part[kq * 256 + pr] = acc;
    }
    __syncthreads();
    if (tid < 256)
      pooled[tid] = (part[tid] + part[256 + tid]) * (1.0f / N_NODES) + bg[h];
    __syncthreads();
    {
      const int k0 = kq * 64;
      float acc = 0.f;
#pragma unroll
      for (int k = 0; k < 64; ++k)
        acc += pooled[hb * HD + k0 + k] * W1[(k0 + k) * HD + h];
      part[kq * 256 + pr] = acc;
    }
    __syncthreads();
    if (tid < 256)
      zz[tid] = fmaxf(part[tid] + part[256 + tid] + b1[h], 0.f);
    __syncthreads();
    if (tid < 256) rf[tid] = zz[tid] * W2[h];
    __syncthreads();
    if (tid < 2) {
      float sm = 0.f;
      for (int k = 0; k < HD; ++k) sm += rf[tid * HD + k];
      out[tid] = sm + b2[0];
    }
  }
}

// ============ fallback (ws too small; never expected to trigger) ============
__global__ void k_init(int* __restrict__ deg, float* __restrict__ s,
                       float* __restrict__ vacc) {
  int i = blockIdx.x * 256 + threadIdx.x;
  if (i < N_NODES) { deg[i] = 1; s[i] = 0.f; }
  if (i < 2 * HD) vacc[i] = 0.f;
}
__global__ void k_deg_at(const int* __restrict__ dst, int* __restrict__ deg, int E) {
  int i = blockIdx.x * 256 + threadIdx.x;
  if (i < E) atomicAdd(&deg[dst[i]], 1);
}
__global__ void k_s_at(const int* __restrict__ src, const int* __restrict__ dst,
                       const int* __restrict__ deg, float* __restrict__ s, int E) {
  int i = blockIdx.x * 256 + threadIdx.x;
  if (i < E) {
    float dv = rsqrtf((float)deg[dst[i]]);
    atomicAdd(&s[src[i]], dv);
  }
}
__global__ void k_w_at(const int* __restrict__ deg, float* __restrict__ s) {
  int i = blockIdx.x * 256 + threadIdx.x;
  if (i < N_NODES) {
    float dv = rsqrtf((float)deg[i]);
    s[i] = dv * (s[i] + dv);
  }
}
__global__ __launch_bounds__(256, 2) void k_main_fb(
    const float* __restrict__ x, const float* __restrict__ Wf,
    const float* __restrict__ bfeat, const float* __restrict__ w,
    float* __restrict__ vacc) {
  __shared__ __align__(16) short lW[32 * 64 * 8];
  const int tid = threadIdx.x;
  for (int c = tid; c < 2048; c += 256) {
    int lane = c & 63, t = (c >> 6) & 7, kt = c >> 9;
    int h = t * 16 + (lane & 15);
    int dbase = kt * 32 + (lane >> 4) * 8;
    short8 v;
#pragma unroll
    for (int j = 0; j < 8; ++j) v[j] = f2bf(Wf[(dbase + j) * HD + h]);
    *(short8*)&lW[c * 8] = v;
  }
  __syncthreads();
  const int lane = tid & 63, wave = tid >> 6;
  const int col = lane & 15, quad = lane >> 4;
  const int b = blockIdx.y;
  float bias[8];
#pragma unroll
  for (int t = 0; t < 8; ++t) bias[t] = bfeat[t * 16 + col];
  float pv[8];
#pragma unroll
  for (int t = 0; t < 8; ++t) pv[t] = 0.f;
  const float* xb = x + (size_t)b * N_NODES * HD;
  for (int tile = blockIdx.x * 4 + wave; tile < NTILES; tile += gridDim.x * 4) {
    const int n0 = tile * 16;
    const float* xr = xb + (size_t)(n0 + col) * HD + quad * 8;
    floatx4 acc[8] = {};
#pragma unroll
    for (int kt = 0; kt < 4; ++kt) {
      floatx4 xlo = *(const floatx4*)(xr + kt * 32);
      floatx4 xhi = *(const floatx4*)(xr + kt * 32 + 4);
      short8 a;
#pragma unroll
      for (int j = 0; j < 4; ++j) { a[j] = f2bf(xlo[j]); a[j + 4] = f2bf(xhi[j]); }
#pragma unroll
      for (int t = 0; t < 8; ++t) {
        short8 bfr = *(const short8*)&lW[((kt * 8 + t) * 64 + lane) * 8];
        acc[t] = __builtin_amdgcn_mfma_f32_16x16x32_bf16(a, bfr, acc[t], 0, 0, 0);
      }
    }
    floatx4 w4 = *(const floatx4*)&w[n0 + quad * 4];
#pragma unroll
    for (int t = 0; t < 8; ++t)
#pragma unroll
      for (int r = 0; r < 4; ++r) {
        float y = acc[t][r] + bias[t];
        pv[t] += fmaxf(y, 0.f) * w4[r];
      }
  }
  __syncthreads();
  float* red = (float*)lW;
#pragma unroll
  for (int t = 0; t < 8; ++t) {
    float v = pv[t];
    v += __shfl_xor(v, 32, 64);
    v += __shfl_xor(v, 16, 64);
    if (quad == 0) red[wave * 128 + t * 16 + col] = v;
  }
  __syncthreads();
  if (tid < 128) {
    float v = red[tid] + red[128 + tid] + red[256 + tid] + red[384 + tid];
    atomicAdd(&vacc[b * HD + tid], v);
  }
}
__global__ void k_final_fb(const float* __restrict__ vacc, const float* __restrict__ Wg,
                           const float* __restrict__ bg, const float* __restrict__ W1,
                           const float* __restrict__ b1, const float* __restrict__ W2,
                           const float* __restrict__ b2, float* __restrict__ out) {
  __shared__ float pooled[2][HD];
  __shared__ float z[2][HD];
  __shared__ float red[256];
  const int tid = threadIdx.x;
  const int b = tid >> 7, h = tid & 127;
  float acc = 0.f;
  for (int k = 0; k < HD; ++k) acc += vacc[b * HD + k] * Wg[k * HD + h];
  pooled[b][h] = acc * (1.0f / N_NODES) + bg[h];
  __syncthreads();
  acc = 0.f;
  for (int k = 0; k < HD; ++k) acc += pooled[b][k] * W1[k * HD + h];
  z[b][h] = fmaxf(acc + b1[h], 0.f);
  __syncthreads();
  red[tid] = z[b][h] * W2[h];
  __syncthreads();
  if (tid < 2) {
    float sum = 0.f;
    for (int k = 0; k < HD; ++k) sum += red[tid * HD + k];
    out[tid] = sum + b2[0];
  }
}

extern "C" void kernel_launch(void* const* d_in, const int* in_sizes, int n_in,
                              void* d_out, int out_size, void* d_ws, size_t ws_size,
                              hipStream_t stream) {
  const float* x  = (const float*)d_in[0];
  const int*   ei = (const int*)d_in[1];
  const float* Wf = (const float*)d_in[2];
  const float* bf = (const float*)d_in[3];
  const float* Wg = (const float*)d_in[4];
  const float* bg = (const float*)d_in[5];
  const float* W1 = (const float*)d_in[6];
  const float* b1 = (const float*)d_in[7];
  const float* W2 = (const float*)d_in[8];
  const float* b2 = (const float*)d_in[9];
  float* out = (float*)d_out;

  const int E = in_sizes[1] / 2;
  const int* src = ei;
  const int* dst = ei + E;

  char* ws = (char*)d_ws;
  const size_t nodeB = (N_NODES * 4 + 255) & ~(size_t)255;   // 200192 B
  const size_t vaccB = NG * 2 * HD * 4;                      // 32 KB
  const size_t cellB = NCELL * 32 * 4;                       // 4 KB
  const size_t needed = 2 * nodeB + vaccB + cellB;           // ~437 KB

  if (ws_size >= needed) {
    float*    degf  = (float*)ws;
    float*    sarr  = (float*)(ws + nodeB);
    float*    vaccp = (float*)(ws + 2 * nodeB);
    unsigned* cells = (unsigned*)(ws + 2 * nodeB + vaccB);

    hipMemsetAsync(ws, 0, needed, stream);   // deg=s=vaccp=cells=0
    k_mega2<<<GRID, BLK, 0, stream>>>(x, src, dst, Wf, bf, Wg, bg, W1, b1,
                                      W2, b2, degf, sarr, vaccp, cells, out, E);
  } else {
    // fallback: device-atomic split path
    int*   deg  = (int*)ws;
    float* s    = (float*)(ws + nodeB);
    float* vacc = (float*)(ws + 2 * nodeB);
    k_init<<<(N_NODES + 255) / 256, 256, 0, stream>>>(deg, s, vacc);
    k_deg_at<<<(E + 255) / 256, 256, 0, stream>>>(dst, deg, E);
    k_s_at<<<(E + 255) / 256, 256, 0, stream>>>(src, dst, deg, s, E);
    k_w_at<<<(N_NODES + 255) / 256, 256, 0, stream>>>(deg, s);
    dim3 grid(256, 2);
    k_main_fb<<<grid, 256, 0, stream>>>(x, Wf, bf, s, vacc);
    k_final_fb<<<1, 256, 0, stream>>>(vacc, Wg, bg, W1, b1, W2, b2, out);
  }
  (void)n_in; (void)out_size; (void)ws_size;
}

// Round 8
// 205.436 us; speedup vs baseline: 1.1324x; 1.1324x over previous
//
#include <hip/hip_runtime.h>
#include <hip/hip_bf16.h>

#define N_NODES 50000
#define HD 128
#define NTILES (N_NODES / 16)   // 3125, exact
#define NSLICE 64               // edge slices for privatized scatter
#define NQUART 12500            // nodes per LDS quarter (50 KB f32 bins)
#define GRID 256                // one block per CU; residency-guaranteed
#define BLK 512                 // 8 waves/block
#define NG 32                   // vaccp shards: 8-deep atomic chains
#define NCELL 32                // barrier counter shards: 8-deep arrive chains

using short8  = __attribute__((ext_vector_type(8))) short;   // 8 x bf16 bits
using floatx4 = __attribute__((ext_vector_type(4))) float;

__device__ __forceinline__ short f2bf(float f) {
  union { float fp; unsigned u; } un; un.fp = f;
  unsigned u = un.u + 0x7fffu + ((un.u >> 16) & 1u);   // RNE
  return (short)(u >> 16);
}

// Sharded grid barrier (R7, empirically correct; ~1us-class arrivals).
// R2 lesson: single-cell arrive = 256-deep RMW chain ~26us. 32 cells 128B
// apart -> 8-deep. Poll = relaxed agent LOADS + wave reduce (no ownership).
__device__ __forceinline__ void gridbar(unsigned* cells, unsigned target) {
  __syncthreads();
  if (threadIdx.x == 0)
    __hip_atomic_fetch_add(&cells[(blockIdx.x & (NCELL - 1)) * 32], 1u,
                           __ATOMIC_RELEASE, __HIP_MEMORY_SCOPE_AGENT);
  if (threadIdx.x < 64) {
    unsigned sum;
    do {
      unsigned v = (threadIdx.x < NCELL)
          ? __hip_atomic_load(&cells[threadIdx.x * 32], __ATOMIC_RELAXED,
                              __HIP_MEMORY_SCOPE_AGENT)
          : 0u;
#pragma unroll
      for (int off = 32; off > 0; off >>= 1) v += __shfl_xor(v, off, 64);
      sum = v;
      if (sum < target) __builtin_amdgcn_s_sleep(8);
    } while (sum < target);
    __builtin_amdgcn_fence(__ATOMIC_ACQUIRE, "agent");
  }
  __syncthreads();
}

// =================== mega3: split-pipeline phases, one launch ===============
// A: deg scatter (LDS bins, slice x quarter)   | bar
// B: dinv = rsqrt(1+sum partial); zero vaccp   | bar
// C: s scatter of dinv[dst] (LDS bins)         | bar
// D: w = dinv*(s+dinv)                         | bar
// E: pipelined MFMA weighted sum (NG-sharded)  | election
// F: head (last arriver only)
#define LOADX(dst, ptr) do {                                        \
    _Pragma("unroll") for (int kk = 0; kk < 4; ++kk) {              \
      dst##0[kk] = *(const floatx4*)((ptr) + kk * 32);              \
      dst##1[kk] = *(const floatx4*)((ptr) + kk * 32 + 4);          \
    } } while (0)

#define COMPUTE(X, W4) do {                                         \
    floatx4 acc[8] = {};                                            \
    _Pragma("unroll") for (int kt = 0; kt < 4; ++kt) {              \
      short8 a;                                                     \
      _Pragma("unroll") for (int j = 0; j < 4; ++j) {               \
        a[j] = f2bf(X##0[kt][j]); a[j + 4] = f2bf(X##1[kt][j]); }   \
      _Pragma("unroll") for (int t = 0; t < 8; ++t) {               \
        short8 bfr = *(const short8*)&lW[((kt * 8 + t) * 64 + lane) * 8]; \
        acc[t] = __builtin_amdgcn_mfma_f32_16x16x32_bf16(a, bfr, acc[t], 0, 0, 0); } } \
    _Pragma("unroll") for (int t = 0; t < 8; ++t)                   \
      _Pragma("unroll") for (int r = 0; r < 4; ++r) {               \
        float y = acc[t][r] + bias[t];                              \
        pv[t] += fmaxf(y, 0.f) * (W4)[r]; } } while (0)

__global__ __launch_bounds__(BLK, 2) void k_mega3(
    const float* __restrict__ x, const int* __restrict__ src,
    const int* __restrict__ dst, const float* __restrict__ Wf,
    const float* __restrict__ bfeat,
    const float* __restrict__ Wg, const float* __restrict__ bg,
    const float* __restrict__ W1, const float* __restrict__ b1,
    const float* __restrict__ W2, const float* __restrict__ b2,
    float* __restrict__ partial, float* __restrict__ dinv,
    float* __restrict__ w, float* __restrict__ vaccp,
    unsigned* __restrict__ cells, float* __restrict__ out,
    int E, int perSlice) {
  __shared__ __align__(16) char smem[51200];   // bins(48.9K) | lW(32K)+red(4K)
  __shared__ int lastf;
  const int tid = threadIdx.x;
  const int bx  = blockIdx.x;
  const int slice = bx & (NSLICE - 1);
  const int qbase = (bx >> 6) * NQUART;
  const int e0 = slice * perSlice;
  const int e1 = min(e0 + perSlice, E);
  const int nB = bx * BLK + tid;               // merge-phase node index

  // ---- phase A: degree scatter (LDS privatized) ----
  {
    float* bins = (float*)smem;
    for (int i = tid; i < NQUART / 4; i += BLK)
      ((float4*)bins)[i] = make_float4(0.f, 0.f, 0.f, 0.f);
    __syncthreads();
    for (int e = e0 + tid; e < e1; e += BLK) {
      int k = dst[e];
      if ((unsigned)(k - qbase) < (unsigned)NQUART)
        atomicAdd(&bins[k - qbase], 1.0f);     // ds_add_f32
    }
    __syncthreads();
    float* op = partial + (size_t)slice * N_NODES + qbase;
    for (int i = tid; i < NQUART / 4; i += BLK)
      ((float4*)op)[i] = ((const float4*)bins)[i];
  }
  gridbar(cells, GRID);

  // ---- phase B: dinv[n] = rsqrt(1 + sum_s partial[s][n]); zero vaccp ----
  {
    if (nB < NG * 2 * HD) vaccp[nB] = 0.f;
    if (nB < N_NODES) {
      float s = 1.0f;
      for (int sl = 0; sl < NSLICE; ++sl) s += partial[(size_t)sl * N_NODES + nB];
      dinv[nB] = rsqrtf(s);
    }
  }
  gridbar(cells, 2u * GRID);

  // ---- phase C: scatter dinv[dst] into bins[src] ----
  {
    float* bins = (float*)smem;
    for (int i = tid; i < NQUART / 4; i += BLK)
      ((float4*)bins)[i] = make_float4(0.f, 0.f, 0.f, 0.f);
    __syncthreads();
    for (int e = e0 + tid; e < e1; e += BLK) {
      int k = src[e];
      if ((unsigned)(k - qbase) < (unsigned)NQUART)
        atomicAdd(&bins[k - qbase], dinv[dst[e]]);
    }
    __syncthreads();
    float* op = partial + (size_t)slice * N_NODES + qbase;
    for (int i = tid; i < NQUART / 4; i += BLK)
      ((float4*)op)[i] = ((const float4*)bins)[i];
  }
  gridbar(cells, 3u * GRID);

  // ---- phase D: w[n] = dinv*(s + dinv) ----
  {
    if (nB < N_NODES) {
      float s = 0.0f;
      for (int sl = 0; sl < NSLICE; ++sl) s += partial[(size_t)sl * N_NODES + nB];
      float dv = dinv[nB];
      w[nB] = dv * (s + dv);
    }
  }
  gridbar(cells, 4u * GRID);

  // ---- phase E: vaccp[g,b,h] += sum_n w[n]*relu(x[b,n,:]@Wf + bf)[h] ----
  short* lW = (short*)smem;              // 32 KB fragment store
  {
    for (int c = tid; c < 2048; c += BLK) {      // c = (kt*8+t)*64 + lane
      int lane = c & 63, t = (c >> 6) & 7, kt = c >> 9;
      int h = t * 16 + (lane & 15);
      int dbase = kt * 32 + (lane >> 4) * 8;
      short8 v;
#pragma unroll
      for (int j = 0; j < 8; ++j) v[j] = f2bf(Wf[(dbase + j) * HD + h]);
      *(short8*)&lW[c * 8] = v;
    }
    __syncthreads();

    const int lane = tid & 63;
    const int wave = tid >> 6;
    const int col  = lane & 15;
    const int quad = lane >> 4;
    const int gw   = bx * 8 + wave;      // 0..2047
    const int b    = gw & 1;

    float bias[8];
#pragma unroll
    for (int t = 0; t < 8; ++t) bias[t] = bfeat[t * 16 + col];
    float pv[8];
#pragma unroll
    for (int t = 0; t < 8; ++t) pv[t] = 0.f;

    const float* xbase = x + (size_t)b * N_NODES * HD;
#define XPTR(t) (xbase + (size_t)((t) * 16 + col) * HD + quad * 8)
    const int t0 = gw >> 1;              // 0..1023
    const int stride = 1024;

    floatx4 xA0[4], xA1[4], xB0[4], xB1[4];
    floatx4 wA = {}, wB = {};
    LOADX(xA, XPTR(t0));
    wA = *(const floatx4*)&w[t0 * 16 + quad * 4];
    for (int tile = t0; tile < NTILES; tile += 2 * stride) {
      const int t1 = tile + stride, t2 = tile + 2 * stride;
      if (t1 < NTILES) {                 // wave-uniform branch
        LOADX(xB, XPTR(t1));
        wB = *(const floatx4*)&w[t1 * 16 + quad * 4];
      }
      COMPUTE(xA, wA);
      if (t2 < NTILES) {
        LOADX(xA, XPTR(t2));
        wA = *(const floatx4*)&w[t2 * 16 + quad * 4];
      }
      if (t1 < NTILES) COMPUTE(xB, wB);
    }

    // cross-wave LDS reduce, then ONE atomic per (g,b,h) per block (8-deep)
    __syncthreads();
    float* red = (float*)(smem + 32768);
#pragma unroll
    for (int t = 0; t < 8; ++t) {
      float v = pv[t];
      v += __shfl_xor(v, 32, 64);
      v += __shfl_xor(v, 16, 64);
      if (quad == 0) red[wave * 128 + t * 16 + col] = v;
    }
    __syncthreads();
    if (tid < 256) {
      int hb = tid >> 7, h = tid & 127;
      float v = red[hb * 128 + h] + red[(hb + 2) * 128 + h] +
                red[(hb + 4) * 128 + h] + red[(hb + 6) * 128 + h];
      atomicAdd(&vaccp[((bx & (NG - 1)) * 2 + hb) * HD + h], v);
    }
  }

  // ---- election: last arriver runs the head; everyone else exits ----
  __syncthreads();                       // vaccp atomics drained
  if (tid == 0)
    __hip_atomic_fetch_add(&cells[(bx & (NCELL - 1)) * 32], 1u,
                           __ATOMIC_RELEASE, __HIP_MEMORY_SCOPE_AGENT);
  if (tid < 64) {
    unsigned v = (tid < NCELL)
        ? __hip_atomic_load(&cells[tid * 32], __ATOMIC_RELAXED,
                            __HIP_MEMORY_SCOPE_AGENT)
        : 0u;
#pragma unroll
    for (int off = 32; off > 0; off >>= 1) v += __shfl_xor(v, off, 64);
    if (tid == 0) lastf = (v >= 5u * GRID) ? 1 : 0;
  }
  __syncthreads();
  if (!lastf) return;
  __builtin_amdgcn_fence(__ATOMIC_ACQUIRE, "agent");

  // ---- phase F: tiny head (512 threads, 2-way k-split GEMVs) ----
  {
    float* vsum   = (float*)smem;          // 256 floats
    float* pooled = vsum + 256;            // 256
    float* zz     = pooled + 256;          // 256
    float* part   = zz + 256;              // 2*256
    float* rf     = part + 512;            // 256
    const int kq = tid >> 8;               // 0/1
    const int pr = tid & 255;
    const int hb = pr >> 7, h = pr & 127;
    if (tid < 256) {
      float a = 0.f;
#pragma unroll
      for (int g = 0; g < NG; ++g) a += vaccp[g * 256 + tid];
      vsum[tid] = a;
    }
    __syncthreads();
    {
      const int k0 = kq * 64;
      float acc = 0.f;
#pragma unroll
      for (int k = 0; k < 64; ++k)
        acc += vsum[hb * HD + k0 + k] * Wg[(k0 + k) * HD + h];
      part[kq * 256 + pr] = acc;
    }
    __syncthreads();
    if (tid < 256)
      pooled[tid] = (part[tid] + part[256 + tid]) * (1.0f / N_NODES) + bg[h];
    __syncthreads();
    {
      const int k0 = kq * 64;
      float acc = 0.f;
#pragma unroll
      for (int k = 0; k < 64; ++k)
        acc += pooled[hb * HD + k0 + k] * W1[(k0 + k) * HD + h];
      part[kq * 256 + pr] = acc;
    }
    __syncthreads();
    if (tid < 256)
      zz[tid] = fmaxf(part[tid] + part[256 + tid] + b1[h], 0.f);
    __syncthreads();
    if (tid < 256) rf[tid] = zz[tid] * W2[h];
    __syncthreads();
    if (tid < 2) {
      float sm = 0.f;
      for (int k = 0; k < HD; ++k) sm += rf[tid * HD + k];
      out[tid] = sm + b2[0];
    }
  }
}

// ============ fallback (ws too small; never expected to trigger) ============
__global__ void k_init(int* __restrict__ deg, float* __restrict__ s,
                       float* __restrict__ vacc) {
  int i = blockIdx.x * 256 + threadIdx.x;
  if (i < N_NODES) { deg[i] = 1; s[i] = 0.f; }
  if (i < 2 * HD) vacc[i] = 0.f;
}
__global__ void k_deg_at(const int* __restrict__ dst, int* __restrict__ deg, int E) {
  int i = blockIdx.x * 256 + threadIdx.x;
  if (i < E) atomicAdd(&deg[dst[i]], 1);
}
__global__ void k_s_at(const int* __restrict__ src, const int* __restrict__ dst,
                       const int* __restrict__ deg, float* __restrict__ s, int E) {
  int i = blockIdx.x * 256 + threadIdx.x;
  if (i < E) {
    float dv = rsqrtf((float)deg[dst[i]]);
    atomicAdd(&s[src[i]], dv);
  }
}
__global__ void k_w_at(const int* __restrict__ deg, float* __restrict__ s) {
  int i = blockIdx.x * 256 + threadIdx.x;
  if (i < N_NODES) {
    float dv = rsqrtf((float)deg[i]);
    s[i] = dv * (s[i] + dv);
  }
}
__global__ __launch_bounds__(256, 2) void k_main_fb(
    const float* __restrict__ x, const float* __restrict__ Wf,
    const float* __restrict__ bfeat, const float* __restrict__ w,
    float* __restrict__ vacc) {
  __shared__ __align__(16) short lW[32 * 64 * 8];
  const int tid = threadIdx.x;
  for (int c = tid; c < 2048; c += 256) {
    int lane = c & 63, t = (c >> 6) & 7, kt = c >> 9;
    int h = t * 16 + (lane & 15);
    int dbase = kt * 32 + (lane >> 4) * 8;
    short8 v;
#pragma unroll
    for (int j = 0; j < 8; ++j) v[j] = f2bf(Wf[(dbase + j) * HD + h]);
    *(short8*)&lW[c * 8] = v;
  }
  __syncthreads();
  const int lane = tid & 63, wave = tid >> 6;
  const int col = lane & 15, quad = lane >> 4;
  const int b = blockIdx.y;
  float bias[8];
#pragma unroll
  for (int t = 0; t < 8; ++t) bias[t] = bfeat[t * 16 + col];
  float pv[8];
#pragma unroll
  for (int t = 0; t < 8; ++t) pv[t] = 0.f;
  const float* xb = x + (size_t)b * N_NODES * HD;
  for (int tile = blockIdx.x * 4 + wave; tile < NTILES; tile += gridDim.x * 4) {
    const int n0 = tile * 16;
    const float* xr = xb + (size_t)(n0 + col) * HD + quad * 8;
    floatx4 acc[8] = {};
#pragma unroll
    for (int kt = 0; kt < 4; ++kt) {
      floatx4 xlo = *(const floatx4*)(xr + kt * 32);
      floatx4 xhi = *(const floatx4*)(xr + kt * 32 + 4);
      short8 a;
#pragma unroll
      for (int j = 0; j < 4; ++j) { a[j] = f2bf(xlo[j]); a[j + 4] = f2bf(xhi[j]); }
#pragma unroll
      for (int t = 0; t < 8; ++t) {
        short8 bfr = *(const short8*)&lW[((kt * 8 + t) * 64 + lane) * 8];
        acc[t] = __builtin_amdgcn_mfma_f32_16x16x32_bf16(a, bfr, acc[t], 0, 0, 0);
      }
    }
    floatx4 w4 = *(const floatx4*)&w[n0 + quad * 4];
#pragma unroll
    for (int t = 0; t < 8; ++t)
#pragma unroll
      for (int r = 0; r < 4; ++r) {
        float y = acc[t][r] + bias[t];
        pv[t] += fmaxf(y, 0.f) * w4[r];
      }
  }
  __syncthreads();
  float* red = (float*)lW;
#pragma unroll
  for (int t = 0; t < 8; ++t) {
    float v = pv[t];
    v += __shfl_xor(v, 32, 64);
    v += __shfl_xor(v, 16, 64);
    if (quad == 0) red[wave * 128 + t * 16 + col] = v;
  }
  __syncthreads();
  if (tid < 128) {
    float v = red[tid] + red[128 + tid] + red[256 + tid] + red[384 + tid];
    atomicAdd(&vacc[b * HD + tid], v);
  }
}
__global__ void k_final_fb(const float* __restrict__ vacc, const float* __restrict__ Wg,
                           const float* __restrict__ bg, const float* __restrict__ W1,
                           const float* __restrict__ b1, const float* __restrict__ W2,
                           const float* __restrict__ b2, float* __restrict__ out) {
  __shared__ float pooled[2][HD];
  __shared__ float z[2][HD];
  __shared__ float red[256];
  const int tid = threadIdx.x;
  const int b = tid >> 7, h = tid & 127;
  float acc = 0.f;
  for (int k = 0; k < HD; ++k) acc += vacc[b * HD + k] * Wg[k * HD + h];
  pooled[b][h] = acc * (1.0f / N_NODES) + bg[h];
  __syncthreads();
  acc = 0.f;
  for (int k = 0; k < HD; ++k) acc += pooled[b][k] * W1[k * HD + h];
  z[b][h] = fmaxf(acc + b1[h], 0.f);
  __syncthreads();
  red[tid] = z[b][h] * W2[h];
  __syncthreads();
  if (tid < 2) {
    float sum = 0.f;
    for (int k = 0; k < HD; ++k) sum += red[tid * HD + k];
    out[tid] = sum + b2[0];
  }
}

extern "C" void kernel_launch(void* const* d_in, const int* in_sizes, int n_in,
                              void* d_out, int out_size, void* d_ws, size_t ws_size,
                              hipStream_t stream) {
  const float* x  = (const float*)d_in[0];
  const int*   ei = (const int*)d_in[1];
  const float* Wf = (const float*)d_in[2];
  const float* bf = (const float*)d_in[3];
  const float* Wg = (const float*)d_in[4];
  const float* bg = (const float*)d_in[5];
  const float* W1 = (const float*)d_in[6];
  const float* b1 = (const float*)d_in[7];
  const float* W2 = (const float*)d_in[8];
  const float* b2 = (const float*)d_in[9];
  float* out = (float*)d_out;

  const int E = in_sizes[1] / 2;
  const int* src = ei;
  const int* dst = ei + E;
  const int perSlice = (E + NSLICE - 1) / NSLICE;

  char* ws = (char*)d_ws;
  const size_t partialB = (size_t)NSLICE * N_NODES * 4;          // 12.8 MB
  const size_t nodeB    = (N_NODES * 4 + 255) & ~(size_t)255;    // 200192 B
  const size_t vaccB    = NG * 2 * HD * 4;                       // 32 KB
  const size_t cellB    = NCELL * 32 * 4;                        // 4 KB
  const size_t needed   = partialB + 2 * nodeB + vaccB + cellB;

  if (ws_size >= needed) {
    float*    partial = (float*)ws;
    float*    dinv    = (float*)(ws + partialB);
    float*    w       = (float*)(ws + partialB + nodeB);
    float*    vaccp   = (float*)(ws + partialB + 2 * nodeB);
    unsigned* cells   = (unsigned*)(ws + partialB + 2 * nodeB + vaccB);

    hipMemsetAsync(cells, 0, cellB, stream);   // barrier cells only
    k_mega3<<<GRID, BLK, 0, stream>>>(x, src, dst, Wf, bf, Wg, bg, W1, b1,
                                      W2, b2, partial, dinv, w, vaccp,
                                      cells, out, E, perSlice);
  } else {
    // fallback: device-atomic split path
    int*   deg  = (int*)ws;
    float* s    = (float*)(ws + nodeB);
    float* vacc = (float*)(ws + 2 * nodeB);
    k_init<<<(N_NODES + 255) / 256, 256, 0, stream>>>(deg, s, vacc);
    k_deg_at<<<(E + 255) / 256, 256, 0, stream>>>(dst, deg, E);
    k_s_at<<<(E + 255) / 256, 256, 0, stream>>>(src, dst, deg, s, E);
    k_w_at<<<(N_NODES + 255) / 256, 256, 0, stream>>>(deg, s);
    dim3 grid(128, 2);
    k_main_fb<<<grid, 256, 0, stream>>>(x, Wf, bf, s, vacc);
    k_final_fb<<<1, 256, 0, stream>>>(vacc, Wg, bg, W1, b1, W2, b2, out);
  }
  (void)n_in; (void)out_size; (void)ws_size;
}

// Round 10
// 169.015 us; speedup vs baseline: 1.3764x; 1.2155x over previous
//
#include <hip/hip_runtime.h>
#include <hip/hip_bf16.h>

#define N_NODES 50000
#define HD 128
#define NTILES (N_NODES / 16)   // 3125, exact
#define NSLICE 32               // edge slices (R9: halved -> partial 6.4MB)
#define NQUART 12500            // nodes per LDS quarter (50 KB f32 bins)
#define GRIDAB (NSLICE * 4)     // 128 blocks for the fused edge kernels
#define NG 32                   // vaccp shards: 8-deep atomic chains
#define NCELL 32                // barrier counter shards

using short8  = __attribute__((ext_vector_type(8))) short;   // 8 x bf16 bits
using floatx4 = __attribute__((ext_vector_type(4))) float;

__device__ __forceinline__ short f2bf(float f) {
  union { float fp; unsigned u; } un; un.fp = f;
  unsigned u = un.u + 0x7fffu + ((un.u >> 16) & 1u);   // RNE
  return (short)(u >> 16);
}

// Sharded grid barrier (validated R7/R8: correct, ~us-class).
// Arrive: ONE release RMW to cell[bx%32] (cells 128B apart, 4-deep chains at
// 128 blocks). Poll: relaxed agent LOADS + wave reduce. Monotonic targets —
// cells are zeroed once per iteration and count across BOTH fused kernels
// (safe: same-stream kernels serialize, so k_CD starts only after k_AB's
// 128 arrivals are all in; stale over-counted cells during rocprof replay
// make the poll exit immediately — never a hang).
__device__ __forceinline__ void gridbar(unsigned* cells, unsigned target) {
  __syncthreads();
  if (threadIdx.x == 0)
    __hip_atomic_fetch_add(&cells[(blockIdx.x & (NCELL - 1)) * 32], 1u,
                           __ATOMIC_RELEASE, __HIP_MEMORY_SCOPE_AGENT);
  if (threadIdx.x < 64) {
    unsigned sum;
    do {
      unsigned v = (threadIdx.x < NCELL)
          ? __hip_atomic_load(&cells[threadIdx.x * 32], __ATOMIC_RELAXED,
                              __HIP_MEMORY_SCOPE_AGENT)
          : 0u;
#pragma unroll
      for (int off = 32; off > 0; off >>= 1) v += __shfl_xor(v, off, 64);
      sum = v;
      if (sum < target) __builtin_amdgcn_s_sleep(8);
    } while (sum < target);
    __builtin_amdgcn_fence(__ATOMIC_ACQUIRE, "agent");
  }
  __syncthreads();
}

// ============ fused edge kernel 1: [A: deg scatter | bar | B: dinv] =========
__global__ __launch_bounds__(1024) void k_AB(
    const int* __restrict__ dstk, float* __restrict__ partial,
    float* __restrict__ dinv, float* __restrict__ vaccp,
    unsigned* __restrict__ cells, int E, int perSlice) {
  __shared__ __align__(16) float bins[NQUART];
  const int tid = threadIdx.x;
  const int bx  = blockIdx.x;
  const int slice = bx & (NSLICE - 1);
  const int qbase = (bx >> 5) * NQUART;        // bx/NSLICE
  const int e0 = slice * perSlice;
  const int e1 = min(e0 + perSlice, E);

  // ---- phase A: degree scatter (LDS privatized) ----
  for (int i = tid; i < NQUART / 4; i += 1024)
    ((float4*)bins)[i] = make_float4(0.f, 0.f, 0.f, 0.f);
  __syncthreads();
  for (int e = e0 + tid; e < e1; e += 1024) {
    int k = dstk[e];
    if ((unsigned)(k - qbase) < (unsigned)NQUART)
      atomicAdd(&bins[k - qbase], 1.0f);       // ds_add_f32
  }
  __syncthreads();
  {
    float* op = partial + (size_t)slice * N_NODES + qbase;
    for (int i = tid; i < NQUART / 4; i += 1024)
      ((float4*)op)[i] = ((const float4*)bins)[i];
  }
  gridbar(cells, GRIDAB);

  // ---- phase B: dinv[n] = rsqrt(1 + sum_s partial[s][n]); zero vaccp ----
  // 4 independent accumulators, fully unrolled -> parallel load streams.
  {
    const int nB = bx * 1024 + tid;            // 131072 >= 50000
    if (nB < NG * 2 * HD) vaccp[nB] = 0.f;
    if (nB < N_NODES) {
      float s0 = 1.0f, s1 = 0.f, s2 = 0.f, s3 = 0.f;
#pragma unroll
      for (int sl = 0; sl < NSLICE; sl += 4) {
        s0 += partial[(size_t)(sl + 0) * N_NODES + nB];
        s1 += partial[(size_t)(sl + 1) * N_NODES + nB];
        s2 += partial[(size_t)(sl + 2) * N_NODES + nB];
        s3 += partial[(size_t)(sl + 3) * N_NODES + nB];
      }
      dinv[nB] = rsqrtf((s0 + s1) + (s2 + s3));
    }
  }
}

// ======== fused edge kernel 2: [C: s scatter of dinv[dst] | bar | D: w] =====
__global__ __launch_bounds__(1024) void k_CD(
    const int* __restrict__ srck, const int* __restrict__ dstk,
    const float* __restrict__ dinv, float* __restrict__ partial,
    float* __restrict__ w, unsigned* __restrict__ cells,
    int E, int perSlice) {
  __shared__ __align__(16) float bins[NQUART];
  const int tid = threadIdx.x;
  const int bx  = blockIdx.x;
  const int slice = bx & (NSLICE - 1);
  const int qbase = (bx >> 5) * NQUART;
  const int e0 = slice * perSlice;
  const int e1 = min(e0 + perSlice, E);

  // ---- phase C: scatter dinv[dst] into bins[src] ----
  for (int i = tid; i < NQUART / 4; i += 1024)
    ((float4*)bins)[i] = make_float4(0.f, 0.f, 0.f, 0.f);
  __syncthreads();
  for (int e = e0 + tid; e < e1; e += 1024) {
    int k = srck[e];
    if ((unsigned)(k - qbase) < (unsigned)NQUART)
      atomicAdd(&bins[k - qbase], dinv[dstk[e]]);
  }
  __syncthreads();
  {
    float* op = partial + (size_t)slice * N_NODES + qbase;
    for (int i = tid; i < NQUART / 4; i += 1024)
      ((float4*)op)[i] = ((const float4*)bins)[i];
  }
  gridbar(cells, 2u * GRIDAB);   // cells carry over from k_AB (monotonic)

  // ---- phase D: w[n] = dinv*(s + dinv) ----
  {
    const int nB = bx * 1024 + tid;
    if (nB < N_NODES) {
      float s0 = 0.f, s1 = 0.f, s2 = 0.f, s3 = 0.f;
#pragma unroll
      for (int sl = 0; sl < NSLICE; sl += 4) {
        s0 += partial[(size_t)(sl + 0) * N_NODES + nB];
        s1 += partial[(size_t)(sl + 1) * N_NODES + nB];
        s2 += partial[(size_t)(sl + 2) * N_NODES + nB];
        s3 += partial[(size_t)(sl + 3) * N_NODES + nB];
      }
      float dv = dinv[nB];
      w[nB] = dv * (((s0 + s1) + (s2 + s3)) + dv);
    }
  }
}

// ---- main: vaccp[g,b,h] += sum_n w[n] * relu(x[b,n,:] @ W_feat + b_feat)[h]
// R6-verbatim (best known): grid(256,2), NG=32 sharded atomics, 2-stage
// software pipeline.
#define LOADX(dst, ptr) do {                                        \
    _Pragma("unroll") for (int kk = 0; kk < 4; ++kk) {              \
      dst##0[kk] = *(const floatx4*)((ptr) + kk * 32);              \
      dst##1[kk] = *(const floatx4*)((ptr) + kk * 32 + 4);          \
    } } while (0)

#define COMPUTE(X, W4) do {                                         \
    floatx4 acc[8] = {};                                            \
    _Pragma("unroll") for (int kt = 0; kt < 4; ++kt) {              \
      short8 a;                                                     \
      _Pragma("unroll") for (int j = 0; j < 4; ++j) {               \
        a[j] = f2bf(X##0[kt][j]); a[j + 4] = f2bf(X##1[kt][j]); }   \
      _Pragma("unroll") for (int t = 0; t < 8; ++t) {               \
        short8 bfr = *(const short8*)&lW[((kt * 8 + t) * 64 + lane) * 8]; \
        acc[t] = __builtin_amdgcn_mfma_f32_16x16x32_bf16(a, bfr, acc[t], 0, 0, 0); } } \
    _Pragma("unroll") for (int t = 0; t < 8; ++t)                   \
      _Pragma("unroll") for (int r = 0; r < 4; ++r) {               \
        float y = acc[t][r] + bias[t];                              \
        pv[t] += fmaxf(y, 0.f) * (W4)[r]; } } while (0)

__global__ __launch_bounds__(256, 2) void k_main(
    const float* __restrict__ x, const float* __restrict__ Wf,
    const float* __restrict__ bfeat, const float* __restrict__ w,
    float* __restrict__ vaccp) {
  __shared__ __align__(16) short lW[32 * 64 * 8];   // 32 KB
  const int tid = threadIdx.x;
  for (int c = tid; c < 2048; c += 256) {           // c = (kt*8+t)*64 + lane
    int lane = c & 63, t = (c >> 6) & 7, kt = c >> 9;
    int h = t * 16 + (lane & 15);
    int dbase = kt * 32 + (lane >> 4) * 8;
    short8 v;
#pragma unroll
    for (int j = 0; j < 8; ++j) v[j] = f2bf(Wf[(dbase + j) * HD + h]);
    *(short8*)&lW[c * 8] = v;
  }
  __syncthreads();

  const int lane = tid & 63;
  const int wave = tid >> 6;
  const int col  = lane & 15;
  const int quad = lane >> 4;
  const int b    = blockIdx.y;
  const int g    = blockIdx.x & (NG - 1);

  float bias[8];
#pragma unroll
  for (int t = 0; t < 8; ++t) bias[t] = bfeat[t * 16 + col];
  float pv[8];
#pragma unroll
  for (int t = 0; t < 8; ++t) pv[t] = 0.f;

  const float* xbase = x + (size_t)b * N_NODES * HD;
#define XPTR(t) (xbase + (size_t)((t) * 16 + col) * HD + quad * 8)

  const int stride = gridDim.x * 4;      // 1024 wave-slots per batch
  const int t0 = blockIdx.x * 4 + wave;  // < 1024 < NTILES always

  floatx4 xA0[4], xA1[4], xB0[4], xB1[4];
  floatx4 wA = {}, wB = {};
  LOADX(xA, XPTR(t0));
  wA = *(const floatx4*)&w[t0 * 16 + quad * 4];
  for (int tile = t0; tile < NTILES; tile += 2 * stride) {
    const int t1 = tile + stride, t2 = tile + 2 * stride;
    if (t1 < NTILES) {                   // wave-uniform branch
      LOADX(xB, XPTR(t1));
      wB = *(const floatx4*)&w[t1 * 16 + quad * 4];
    }
    COMPUTE(xA, wA);                     // waits only on xA's loads
    if (t2 < NTILES) {
      LOADX(xA, XPTR(t2));
      wA = *(const floatx4*)&w[t2 * 16 + quad * 4];
    }
    if (t1 < NTILES) COMPUTE(xB, wB);
  }

  // cross-wave LDS reduce, then ONE atomic per (g,b,h) per block (8-deep)
  __syncthreads();
  float* red = (float*)lW;
#pragma unroll
  for (int t = 0; t < 8; ++t) {
    float v = pv[t];
    v += __shfl_xor(v, 32, 64);
    v += __shfl_xor(v, 16, 64);
    if (quad == 0) red[wave * 128 + t * 16 + col] = v;
  }
  __syncthreads();
  if (tid < 128) {
    float v = red[tid] + red[128 + tid] + red[256 + tid] + red[384 + tid];
    atomicAdd(&vaccp[(g * 2 + b) * HD + tid], v);
  }
}

// ---- tiny head: 32-group pre-sum + 4-way k-split GEMVs (R6-verbatim) ----
__global__ __launch_bounds__(1024) void k_final(
    const float* __restrict__ vaccp, const float* __restrict__ Wg,
    const float* __restrict__ bg, const float* __restrict__ W1,
    const float* __restrict__ b1, const float* __restrict__ W2,
    const float* __restrict__ b2, float* __restrict__ out) {
  __shared__ float part[4][256];
  __shared__ float vsum[256];
  __shared__ float pooled[2][HD];
  __shared__ float z[2][HD];
  __shared__ float red[256];
  const int tid = threadIdx.x;
  const int kq = tid >> 8;
  const int pr = tid & 255;
  const int b  = pr >> 7, h = pr & 127;
  {
    float acc = 0.f;
#pragma unroll
    for (int j = 0; j < 8; ++j)
      acc += vaccp[(kq * 8 + j) * 2 * HD + pr];
    part[kq][pr] = acc;
  }
  __syncthreads();
  if (tid < 256)
    vsum[tid] = part[0][tid] + part[1][tid] + part[2][tid] + part[3][tid];
  __syncthreads();
  {
    const int k0 = kq * 32;
    float acc = 0.f;
#pragma unroll
    for (int k = 0; k < 32; ++k)
      acc += vsum[b * HD + k0 + k] * Wg[(k0 + k) * HD + h];
    part[kq][pr] = acc;
  }
  __syncthreads();
  if (tid < 256) {
    float acc = part[0][tid] + part[1][tid] + part[2][tid] + part[3][tid];
    pooled[b][h] = acc * (1.0f / N_NODES) + bg[h];
  }
  __syncthreads();
  {
    const int k0 = kq * 32;
    float acc = 0.f;
#pragma unroll
    for (int k = 0; k < 32; ++k)
      acc += pooled[b][k0 + k] * W1[(k0 + k) * HD + h];
    part[kq][pr] = acc;
  }
  __syncthreads();
  if (tid < 256) {
    float acc = part[0][tid] + part[1][tid] + part[2][tid] + part[3][tid];
    z[b][h] = fmaxf(acc + b1[h], 0.f);
  }
  __syncthreads();
  if (tid < 256) red[tid] = z[b][h] * W2[h];
  __syncthreads();
  if (tid < 2) {
    float s = 0.f;
    for (int k = 0; k < HD; ++k) s += red[tid * HD + k];
    out[tid] = s + b2[0];
  }
}

// =======================  fallback (device atomics)  ========================
__global__ void k_init(int* __restrict__ deg, float* __restrict__ s,
                       float* __restrict__ vaccp) {
  int i = blockIdx.x * 256 + threadIdx.x;
  if (i < N_NODES) { deg[i] = 1; s[i] = 0.f; }
  if (i < NG * 2 * HD) vaccp[i] = 0.f;
}
__global__ void k_deg_at(const int* __restrict__ dst, int* __restrict__ deg, int E) {
  int i = blockIdx.x * 256 + threadIdx.x;
  if (i < E) atomicAdd(&deg[dst[i]], 1);
}
__global__ void k_s_at(const int* __restrict__ src, const int* __restrict__ dst,
                       const int* __restrict__ deg, float* __restrict__ s, int E) {
  int i = blockIdx.x * 256 + threadIdx.x;
  if (i < E) {
    float dv = rsqrtf((float)deg[dst[i]]);
    atomicAdd(&s[src[i]], dv);
  }
}
__global__ void k_w_at(const int* __restrict__ deg, float* __restrict__ s) {
  int i = blockIdx.x * 256 + threadIdx.x;
  if (i < N_NODES) {
    float dv = rsqrtf((float)deg[i]);
    s[i] = dv * (s[i] + dv);
  }
}

extern "C" void kernel_launch(void* const* d_in, const int* in_sizes, int n_in,
                              void* d_out, int out_size, void* d_ws, size_t ws_size,
                              hipStream_t stream) {
  const float* x  = (const float*)d_in[0];
  const int*   ei = (const int*)d_in[1];
  const float* Wf = (const float*)d_in[2];
  const float* bf = (const float*)d_in[3];
  const float* Wg = (const float*)d_in[4];
  const float* bg = (const float*)d_in[5];
  const float* W1 = (const float*)d_in[6];
  const float* b1 = (const float*)d_in[7];
  const float* W2 = (const float*)d_in[8];
  const float* b2 = (const float*)d_in[9];
  float* out = (float*)d_out;

  const int E = in_sizes[1] / 2;
  const int* src = ei;
  const int* dst = ei + E;
  const int perSlice = (E + NSLICE - 1) / NSLICE;

  char* ws = (char*)d_ws;
  const size_t partialB = (size_t)NSLICE * N_NODES * 4;          // 6.4 MB
  const size_t nodeB    = (N_NODES * 4 + 255) & ~(size_t)255;    // 200192 B
  const size_t vaccB    = NG * 2 * HD * 4;                       // 32 KB
  const size_t cellB    = NCELL * 32 * 4;                        // 4 KB
  const size_t needed   = partialB + 2 * nodeB + vaccB + cellB;

  if (ws_size >= needed) {
    float*    partial = (float*)ws;
    float*    dinv    = (float*)(ws + partialB);
    float*    w       = (float*)(ws + partialB + nodeB);
    float*    vaccp   = (float*)(ws + partialB + 2 * nodeB);
    unsigned* cells   = (unsigned*)(ws + partialB + 2 * nodeB + vaccB);

    hipMemsetAsync(cells, 0, cellB, stream);
    k_AB<<<GRIDAB, 1024, 0, stream>>>(dst, partial, dinv, vaccp, cells, E, perSlice);
    k_CD<<<GRIDAB, 1024, 0, stream>>>(src, dst, dinv, partial, w, cells, E, perSlice);
    dim3 grid(256, 2);                   // 512 blocks, 2/CU, 8 waves/CU
    k_main<<<grid, 256, 0, stream>>>(x, Wf, bf, w, vaccp);
    k_final<<<1, 1024, 0, stream>>>(vaccp, Wg, bg, W1, b1, W2, b2, out);
  } else {
    // fallback: device-atomic path
    int*   deg   = (int*)ws;
    float* s     = (float*)(ws + nodeB);
    float* vaccp = (float*)(ws + 2 * nodeB);
    k_init<<<(N_NODES + 255) / 256, 256, 0, stream>>>(deg, s, vaccp);
    k_deg_at<<<(E + 255) / 256, 256, 0, stream>>>(dst, deg, E);
    k_s_at<<<(E + 255) / 256, 256, 0, stream>>>(src, dst, deg, s, E);
    k_w_at<<<(N_NODES + 255) / 256, 256, 0, stream>>>(deg, s);
    dim3 grid(256, 2);
    k_main<<<grid, 256, 0, stream>>>(x, Wf, bf, s, vaccp);
    k_final<<<1, 1024, 0, stream>>>(vaccp, Wg, bg, W1, b1, W2, b2, out);
  }
  (void)n_in; (void)out_size; (void)ws_size;
}

// Round 11
// 151.847 us; speedup vs baseline: 1.5320x; 1.1131x over previous
//
#include <hip/hip_runtime.h>
#include <hip/hip_bf16.h>

#define N_NODES 50000
#define HD 128
#define NTILES (N_NODES / 16)   // 3125, exact
#define NSLICE 64               // edge slices: NSLICE x 4 = 256 scatter blocks
#define NQUART 12500            // nodes per LDS quarter (50 KB f32 bins)
#define NG 32                   // vaccp shards: 8-deep atomic chains

using short8  = __attribute__((ext_vector_type(8))) short;   // 8 x bf16 bits
using floatx4 = __attribute__((ext_vector_type(4))) float;

__device__ __forceinline__ short f2bf(float f) {
  union { float fp; unsigned u; } un; un.fp = f;
  unsigned u = un.u + 0x7fffu + ((un.u >> 16) & 1u);   // RNE
  return (short)(u >> 16);
}

// =======================  fast edge phase (no device atomics)  ==============
// R0/R6-verbatim: 256 blocks (slice x quarter), LDS-privatized bins,
// non-atomic writeback. R10 lesson: scatter parallelism must stay at 256
// blocks — NSLICE=32 halved the grid and cost +17 us.
template <bool GATHER>
__global__ __launch_bounds__(1024) void k_scatter(
    const int* __restrict__ keys, const int* __restrict__ other,
    const float* __restrict__ dinv, float* __restrict__ partial,
    int E, int perSlice) {
  __shared__ __align__(16) float bins[NQUART];
  const int tid = threadIdx.x;
  for (int i = tid; i < NQUART / 4; i += 1024)
    ((float4*)bins)[i] = make_float4(0.f, 0.f, 0.f, 0.f);
  __syncthreads();

  const int slice = blockIdx.x;
  const int base  = blockIdx.y * NQUART;
  const int e0 = slice * perSlice;
  const int e1 = min(e0 + perSlice, E);
  for (int e = e0 + tid; e < e1; e += 1024) {
    int k = keys[e];
    if ((unsigned)(k - base) < (unsigned)NQUART) {
      float v = GATHER ? dinv[other[e]] : 1.0f;
      atomicAdd(&bins[k - base], v);           // ds_add_f32, LDS-local
    }
  }
  __syncthreads();

  float* out = partial + (size_t)slice * N_NODES + base;
  for (int i = tid; i < NQUART / 4; i += 1024)
    ((float4*)out)[i] = ((const float4*)bins)[i];
}

// dinv[n] = rsqrt(1 + sum_s partial[s][n])   (self-loop -> +1)
// R11: 4 independent accumulators (parallel load streams; same grid/traffic).
__global__ void k_merge_deg(const float* __restrict__ partial,
                            float* __restrict__ dinv) {
  int n = blockIdx.x * 256 + threadIdx.x;
  if (n >= N_NODES) return;
  float s0 = 1.0f, s1 = 0.f, s2 = 0.f, s3 = 0.f;
#pragma unroll
  for (int sl = 0; sl < NSLICE; sl += 4) {
    s0 += partial[(size_t)(sl + 0) * N_NODES + n];
    s1 += partial[(size_t)(sl + 1) * N_NODES + n];
    s2 += partial[(size_t)(sl + 2) * N_NODES + n];
    s3 += partial[(size_t)(sl + 3) * N_NODES + n];
  }
  dinv[n] = rsqrtf((s0 + s1) + (s2 + s3));
}

// w[n] = dinv[n] * (sum_s partial[s][n] + dinv[n]);  also zero vaccp (32 KB)
__global__ void k_merge_w(const float* __restrict__ partial,
                          const float* __restrict__ dinv,
                          float* __restrict__ w, float* __restrict__ vaccp) {
  int n = blockIdx.x * 256 + threadIdx.x;
  if (n < NG * 2 * HD) vaccp[n] = 0.f;
  if (n >= N_NODES) return;
  float s0 = 0.f, s1 = 0.f, s2 = 0.f, s3 = 0.f;
#pragma unroll
  for (int sl = 0; sl < NSLICE; sl += 4) {
    s0 += partial[(size_t)(sl + 0) * N_NODES + n];
    s1 += partial[(size_t)(sl + 1) * N_NODES + n];
    s2 += partial[(size_t)(sl + 2) * N_NODES + n];
    s3 += partial[(size_t)(sl + 3) * N_NODES + n];
  }
  float dv = dinv[n];
  w[n] = dv * (((s0 + s1) + (s2 + s3)) + dv);
}

// =======================  fallback edge phase (device atomics)  =============
__global__ void k_init(int* __restrict__ deg, float* __restrict__ s,
                       float* __restrict__ vaccp) {
  int i = blockIdx.x * 256 + threadIdx.x;
  if (i < N_NODES) { deg[i] = 1; s[i] = 0.f; }
  if (i < NG * 2 * HD) vaccp[i] = 0.f;
}
__global__ void k_deg_at(const int* __restrict__ dst, int* __restrict__ deg, int E) {
  int i = blockIdx.x * 256 + threadIdx.x;
  if (i < E) atomicAdd(&deg[dst[i]], 1);
}
__global__ void k_s_at(const int* __restrict__ src, const int* __restrict__ dst,
                       const int* __restrict__ deg, float* __restrict__ s, int E) {
  int i = blockIdx.x * 256 + threadIdx.x;
  if (i < E) {
    float dv = rsqrtf((float)deg[dst[i]]);
    atomicAdd(&s[src[i]], dv);
  }
}
__global__ void k_w_at(const int* __restrict__ deg, float* __restrict__ s) {
  int i = blockIdx.x * 256 + threadIdx.x;
  if (i < N_NODES) {
    float dv = rsqrtf((float)deg[i]);
    s[i] = dv * (s[i] + dv);
  }
}

// ---- main: vaccp[g,b,h] += sum_n w[n] * relu(x[b,n,:] @ W_feat + b_feat)[h]
// R6-verbatim (best known): grid(256,2), NG=32 sharded atomics, 2-stage
// software pipeline.
#define LOADX(dst, ptr) do {                                        \
    _Pragma("unroll") for (int kk = 0; kk < 4; ++kk) {              \
      dst##0[kk] = *(const floatx4*)((ptr) + kk * 32);              \
      dst##1[kk] = *(const floatx4*)((ptr) + kk * 32 + 4);          \
    } } while (0)

#define COMPUTE(X, W4) do {                                         \
    floatx4 acc[8] = {};                                            \
    _Pragma("unroll") for (int kt = 0; kt < 4; ++kt) {              \
      short8 a;                                                     \
      _Pragma("unroll") for (int j = 0; j < 4; ++j) {               \
        a[j] = f2bf(X##0[kt][j]); a[j + 4] = f2bf(X##1[kt][j]); }   \
      _Pragma("unroll") for (int t = 0; t < 8; ++t) {               \
        short8 bfr = *(const short8*)&lW[((kt * 8 + t) * 64 + lane) * 8]; \
        acc[t] = __builtin_amdgcn_mfma_f32_16x16x32_bf16(a, bfr, acc[t], 0, 0, 0); } } \
    _Pragma("unroll") for (int t = 0; t < 8; ++t)                   \
      _Pragma("unroll") for (int r = 0; r < 4; ++r) {               \
        float y = acc[t][r] + bias[t];                              \
        pv[t] += fmaxf(y, 0.f) * (W4)[r]; } } while (0)

__global__ __launch_bounds__(256, 2) void k_main(
    const float* __restrict__ x, const float* __restrict__ Wf,
    const float* __restrict__ bfeat, const float* __restrict__ w,
    float* __restrict__ vaccp) {
  __shared__ __align__(16) short lW[32 * 64 * 8];   // 32 KB
  const int tid = threadIdx.x;
  for (int c = tid; c < 2048; c += 256) {           // c = (kt*8+t)*64 + lane
    int lane = c & 63, t = (c >> 6) & 7, kt = c >> 9;
    int h = t * 16 + (lane & 15);
    int dbase = kt * 32 + (lane >> 4) * 8;
    short8 v;
#pragma unroll
    for (int j = 0; j < 8; ++j) v[j] = f2bf(Wf[(dbase + j) * HD + h]);
    *(short8*)&lW[c * 8] = v;
  }
  __syncthreads();

  const int lane = tid & 63;
  const int wave = tid >> 6;
  const int col  = lane & 15;
  const int quad = lane >> 4;
  const int b    = blockIdx.y;
  const int g    = blockIdx.x & (NG - 1);

  float bias[8];
#pragma unroll
  for (int t = 0; t < 8; ++t) bias[t] = bfeat[t * 16 + col];
  float pv[8];
#pragma unroll
  for (int t = 0; t < 8; ++t) pv[t] = 0.f;

  const float* xbase = x + (size_t)b * N_NODES * HD;
#define XPTR(t) (xbase + (size_t)((t) * 16 + col) * HD + quad * 8)

  const int stride = gridDim.x * 4;      // 1024 wave-slots per batch
  const int t0 = blockIdx.x * 4 + wave;  // < 1024 < NTILES always

  floatx4 xA0[4], xA1[4], xB0[4], xB1[4];
  floatx4 wA = {}, wB = {};
  LOADX(xA, XPTR(t0));
  wA = *(const floatx4*)&w[t0 * 16 + quad * 4];
  for (int tile = t0; tile < NTILES; tile += 2 * stride) {
    const int t1 = tile + stride, t2 = tile + 2 * stride;
    if (t1 < NTILES) {                   // wave-uniform branch
      LOADX(xB, XPTR(t1));
      wB = *(const floatx4*)&w[t1 * 16 + quad * 4];
    }
    COMPUTE(xA, wA);                     // waits only on xA's loads
    if (t2 < NTILES) {
      LOADX(xA, XPTR(t2));
      wA = *(const floatx4*)&w[t2 * 16 + quad * 4];
    }
    if (t1 < NTILES) COMPUTE(xB, wB);
  }

  // cross-wave LDS reduce, then ONE atomic per (g,b,h) per block (8-deep)
  __syncthreads();
  float* red = (float*)lW;
#pragma unroll
  for (int t = 0; t < 8; ++t) {
    float v = pv[t];
    v += __shfl_xor(v, 32, 64);
    v += __shfl_xor(v, 16, 64);
    if (quad == 0) red[wave * 128 + t * 16 + col] = v;
  }
  __syncthreads();
  if (tid < 128) {
    float v = red[tid] + red[128 + tid] + red[256 + tid] + red[384 + tid];
    atomicAdd(&vaccp[(g * 2 + b) * HD + tid], v);
  }
}

// ---- tiny head: 32-group pre-sum + 4-way k-split GEMVs (R6-verbatim) ----
__global__ __launch_bounds__(1024) void k_final(
    const float* __restrict__ vaccp, const float* __restrict__ Wg,
    const float* __restrict__ bg, const float* __restrict__ W1,
    const float* __restrict__ b1, const float* __restrict__ W2,
    const float* __restrict__ b2, float* __restrict__ out) {
  __shared__ float part[4][256];
  __shared__ float vsum[256];
  __shared__ float pooled[2][HD];
  __shared__ float z[2][HD];
  __shared__ float red[256];
  const int tid = threadIdx.x;
  const int kq = tid >> 8;
  const int pr = tid & 255;
  const int b  = pr >> 7, h = pr & 127;
  {
    float acc = 0.f;
#pragma unroll
    for (int j = 0; j < 8; ++j)
      acc += vaccp[(kq * 8 + j) * 2 * HD + pr];
    part[kq][pr] = acc;
  }
  __syncthreads();
  if (tid < 256)
    vsum[tid] = part[0][tid] + part[1][tid] + part[2][tid] + part[3][tid];
  __syncthreads();
  {
    const int k0 = kq * 32;
    float acc = 0.f;
#pragma unroll
    for (int k = 0; k < 32; ++k)
      acc += vsum[b * HD + k0 + k] * Wg[(k0 + k) * HD + h];
    part[kq][pr] = acc;
  }
  __syncthreads();
  if (tid < 256) {
    float acc = part[0][tid] + part[1][tid] + part[2][tid] + part[3][tid];
    pooled[b][h] = acc * (1.0f / N_NODES) + bg[h];
  }
  __syncthreads();
  {
    const int k0 = kq * 32;
    float acc = 0.f;
#pragma unroll
    for (int k = 0; k < 32; ++k)
      acc += pooled[b][k0 + k] * W1[(k0 + k) * HD + h];
    part[kq][pr] = acc;
  }
  __syncthreads();
  if (tid < 256) {
    float acc = part[0][tid] + part[1][tid] + part[2][tid] + part[3][tid];
    z[b][h] = fmaxf(acc + b1[h], 0.f);
  }
  __syncthreads();
  if (tid < 256) red[tid] = z[b][h] * W2[h];
  __syncthreads();
  if (tid < 2) {
    float s = 0.f;
    for (int k = 0; k < HD; ++k) s += red[tid * HD + k];
    out[tid] = s + b2[0];
  }
}

extern "C" void kernel_launch(void* const* d_in, const int* in_sizes, int n_in,
                              void* d_out, int out_size, void* d_ws, size_t ws_size,
                              hipStream_t stream) {
  const float* x  = (const float*)d_in[0];
  const int*   ei = (const int*)d_in[1];
  const float* Wf = (const float*)d_in[2];
  const float* bf = (const float*)d_in[3];
  const float* Wg = (const float*)d_in[4];
  const float* bg = (const float*)d_in[5];
  const float* W1 = (const float*)d_in[6];
  const float* b1 = (const float*)d_in[7];
  const float* W2 = (const float*)d_in[8];
  const float* b2 = (const float*)d_in[9];
  float* out = (float*)d_out;

  const int E = in_sizes[1] / 2;
  const int* src = ei;
  const int* dst = ei + E;
  const int perSlice = (E + NSLICE - 1) / NSLICE;

  char* ws = (char*)d_ws;
  const size_t partialB = (size_t)NSLICE * N_NODES * 4;          // 12.8 MB
  const size_t nodeB    = (N_NODES * 4 + 255) & ~(size_t)255;    // 200192 B
  const size_t vaccB    = NG * 2 * HD * 4;                       // 32 KB
  const size_t needed   = partialB + 2 * nodeB + vaccB;

  if (ws_size >= needed) {
    float* partial = (float*)ws;
    float* dinv    = (float*)(ws + partialB);
    float* w       = (float*)(ws + partialB + nodeB);
    float* vaccp   = (float*)(ws + partialB + 2 * nodeB);

    dim3 sg(NSLICE, N_NODES / NQUART);   // 64 x 4 = 256 blocks
    k_scatter<false><<<sg, 1024, 0, stream>>>(dst, nullptr, nullptr, partial, E, perSlice);
    k_merge_deg<<<(N_NODES + 255) / 256, 256, 0, stream>>>(partial, dinv);
    k_scatter<true><<<sg, 1024, 0, stream>>>(src, dst, dinv, partial, E, perSlice);
    k_merge_w<<<(N_NODES + 255) / 256, 256, 0, stream>>>(partial, dinv, w, vaccp);
    dim3 grid(256, 2);                   // 512 blocks, 2/CU, 8 waves/CU
    k_main<<<grid, 256, 0, stream>>>(x, Wf, bf, w, vaccp);
    k_final<<<1, 1024, 0, stream>>>(vaccp, Wg, bg, W1, b1, W2, b2, out);
  } else {
    // fallback: device-atomic path
    int*   deg   = (int*)ws;
    float* s     = (float*)(ws + nodeB);
    float* vaccp = (float*)(ws + 2 * nodeB);
    k_init<<<(N_NODES + 255) / 256, 256, 0, stream>>>(deg, s, vaccp);
    k_deg_at<<<(E + 255) / 256, 256, 0, stream>>>(dst, deg, E);
    k_s_at<<<(E + 255) / 256, 256, 0, stream>>>(src, dst, deg, s, E);
    k_w_at<<<(N_NODES + 255) / 256, 256, 0, stream>>>(deg, s);
    dim3 grid(256, 2);
    k_main<<<grid, 256, 0, stream>>>(x, Wf, bf, s, vaccp);
    k_final<<<1, 1024, 0, stream>>>(vaccp, Wg, bg, W1, b1, W2, b2, out);
  }
  (void)n_in; (void)out_size; (void)ws_size;
}